// Round 11
// baseline (50.780 us; speedup 1.0000x reference)
//
#include <hip/hip_runtime.h>
#include <hip/hip_bf16.h>

#define TWOPI_OVER_B 0.049087385212340517f  // 2*pi/128

typedef __attribute__((ext_vector_type(8))) short bf16x8;
typedef __attribute__((ext_vector_type(4))) float f32x4;

static __device__ __forceinline__ unsigned short f2bf(float f) {
    __hip_bfloat16 h = __float2bfloat16(f);
    return *reinterpret_cast<unsigned short*>(&h);
}
static __device__ __forceinline__ unsigned long long pack4(float a, float b, float c, float d) {
    return (unsigned long long)f2bf(a) | ((unsigned long long)f2bf(b) << 16)
         | ((unsigned long long)f2bf(c) << 32) | ((unsigned long long)f2bf(d) << 48);
}

// ---------------------------------------------------------------------------
// R3-verbatim: DFT matrices in MFMA B-fragment order.
__global__ __launch_bounds__(256) void k_init_frag(unsigned short* __restrict__ fragB,
                                                   unsigned short* __restrict__ fragCi) {
    int i = blockIdx.x * 256 + threadIdx.x;
    if (i < 18432) {                       // fragB: ((c*4+kb)*64 + l)*8 + e
        int e = i & 7, l = (i >> 3) & 63, kb = (i >> 9) & 3, c = i >> 11;
        int kr = c * 16 + (l & 15);
        int t  = kb * 32 + (l >> 4) * 8 + e;
        float v = 0.f;
        if (kr < 65)       v =  cosf(TWOPI_OVER_B * (float)((kr * t) & 127));
        else if (kr < 130) v = -sinf(TWOPI_OVER_B * (float)(((kr - 65) * t) & 127));
        fragB[i] = f2bf(v);
    }
    if (i < 20480) {                       // fragCi: ((c*5+kb)*64 + l)*8 + e
        int e = i & 7, l = (i >> 3) & 63;
        int ckb = i >> 9; int kb = ckb % 5, c = ckb / 5;
        int kr = kb * 32 + (l >> 4) * 8 + e;
        int t  = c * 16 + (l & 15);
        float v = 0.f;
        if (kr < 65)       v =  cosf(TWOPI_OVER_B * (float)((kr * t) & 127));
        else if (kr < 130) v = -sinf(TWOPI_OVER_B * (float)(((kr - 65) * t) & 127));
        fragCi[i] = f2bf(v);
    }
}

// ---------------------------------------------------------------------------
// R3-verbatim: W spectrum -> BmatT[k][o2][j2] (real-expanded, scale-folded).
__global__ __launch_bounds__(256) void k_wfs_mfma(const float* __restrict__ W,
                                                  const bf16x8* __restrict__ fragB,
                                                  unsigned short* __restrict__ BmatT) {
    __shared__ char smem[37120];
    unsigned long long* xs8 = (unsigned long long*)smem;
    float* Yl = (float*)smem;
    int tid = threadIdx.x;
    int o0 = blockIdx.x * 2;

    #pragma unroll
    for (int it = 0; it < 8; ++it) {        // 64 rows x 128 = 2048 float4
        int f  = tid + it * 256;
        float4 wa = ((const float4*)W)[(size_t)blockIdx.x * 2048 + f];
        int rl = f >> 5;
        int t0 = (f & 31) * 4;
        int byte = (rl * 256 + t0 * 2) ^ ((rl & 7) << 4);
        xs8[byte >> 3] = pack4(wa.x, wa.y, wa.z, wa.w);
    }
    __syncthreads();

    int l = tid & 63, w = tid >> 6;
    int rl_a = w * 16 + (l & 15);
    int coff = (l >> 4) * 16;
    bf16x8 a[4];
    #pragma unroll
    for (int kb = 0; kb < 4; ++kb) {
        int byte = (rl_a * 256 + kb * 64 + coff) ^ ((rl_a & 7) << 4);
        a[kb] = *(const bf16x8*)(smem + byte);
    }
    f32x4 acc[9];
    #pragma unroll
    for (int c = 0; c < 9; ++c) acc[c] = (f32x4)0.f;
    #pragma unroll
    for (int c = 0; c < 9; ++c)
        #pragma unroll
        for (int kb = 0; kb < 4; ++kb)
            acc[c] = __builtin_amdgcn_mfma_f32_16x16x32_bf16(a[kb], fragB[(c * 4 + kb) * 64 + l], acc[c], 0, 0, 0);
    __syncthreads();

    int rowd = w * 16 + (l >> 4) * 4;
    int cold = l & 15;
    #pragma unroll
    for (int c = 0; c < 9; ++c)
        #pragma unroll
        for (int r = 0; r < 4; ++r)
            Yl[(rowd + r) * 145 + c * 16 + cold] = acc[c][r];
    __syncthreads();

    for (int c2 = tid; c2 < 4160; c2 += 256) {
        int k = c2 >> 6, sub = c2 & 63;
        int oo = sub >> 5, h = (sub >> 4) & 1, t = sub & 15;
        int j0 = t * 4;
        float sc = (k == 0 || k == 64) ? (1.f / 128.f) : (2.f / 128.f);
        int col; float sgn;
        if (j0 < 32) { col = h ? 65 + k : k;  sgn = h ? -sc : sc; }
        else         { col = h ? k : 65 + k;  sgn = sc; }
        int rlb = oo * 32 + (j0 & 31);
        unsigned long long pk = pack4(sgn * Yl[(rlb + 0) * 145 + col], sgn * Yl[(rlb + 1) * 145 + col],
                                      sgn * Yl[(rlb + 2) * 145 + col], sgn * Yl[(rlb + 3) * 145 + col]);
        int o2 = h * 32 + o0 + oo;
        *(unsigned long long*)(BmatT + ((size_t)k * 64 + o2) * 64 + j0) = pk;
    }
}

// ---------------------------------------------------------------------------
// Stage A: R3 body, c-split across 2 blocks per n-pair (1024 blocks).
// bid&511 = n-pair; bid>>9 = c-half (0: c 0-4, 1: c 5-8). Sibling blocks
// are 512 apart -> same XCD under round-robin -> staged x L2-hits.
__global__ __launch_bounds__(256) void k_fdft(const float* __restrict__ x,
                                              const float* __restrict__ D,
                                              const bf16x8* __restrict__ fragB,
                                              unsigned short* __restrict__ Xb) {
    __shared__ char smem[37120];   // xs 16384 ∪ Yl 64*145*4
    unsigned long long* xs8 = (unsigned long long*)smem;
    float* Yl = (float*)smem;
    int tid = threadIdx.x;
    int np = blockIdx.x & 511, ch = blockIdx.x >> 9;
    int cbase = ch ? 5 : 0, cn = ch ? 4 : 5;
    int n0 = np * 2;

    #pragma unroll
    for (int it = 0; it < 8; ++it) {       // 2048 float4 = 2 rows of x
        int f  = tid + it * 256;
        int nn = f >> 10;
        int f4 = f & 1023;
        float4 xa = ((const float4*)(x + (size_t)(n0 + nn) * 4096))[f4];
        float4 da = ((const float4*)D)[f4];
        int rl = nn * 32 + (f4 >> 5);
        int t0 = (f4 & 31) * 4;
        int byte = (rl * 256 + t0 * 2) ^ ((rl & 7) << 4);
        xs8[byte >> 3] = pack4(xa.x * da.x, xa.y * da.y, xa.z * da.z, xa.w * da.w);
    }
    __syncthreads();

    int l = tid & 63, w = tid >> 6;
    int rl_a = w * 16 + (l & 15);
    int coff = (l >> 4) * 16;
    bf16x8 a[4];
    #pragma unroll
    for (int kb = 0; kb < 4; ++kb) {
        int byte = (rl_a * 256 + kb * 64 + coff) ^ ((rl_a & 7) << 4);
        a[kb] = *(const bf16x8*)(smem + byte);
    }
    f32x4 acc[5];
    #pragma unroll
    for (int ci = 0; ci < 5; ++ci) acc[ci] = (f32x4)0.f;
    #pragma unroll
    for (int ci = 0; ci < 5; ++ci) {
        int c = cbase + ci;
        if (c < 9) {
            #pragma unroll
            for (int kb = 0; kb < 4; ++kb)
                acc[ci] = __builtin_amdgcn_mfma_f32_16x16x32_bf16(a[kb], fragB[(c * 4 + kb) * 64 + l], acc[ci], 0, 0, 0);
        }
    }
    __syncthreads();                        // xs dead; reuse as Yl

    int rowd = w * 16 + (l >> 4) * 4;
    int cold = l & 15;
    #pragma unroll
    for (int ci = 0; ci < 5; ++ci) {
        int c = cbase + ci;
        if (c < 9) {
            #pragma unroll
            for (int r = 0; r < 4; ++r)
                Yl[(rowd + r) * 145 + c * 16 + cold] = acc[ci][r];
        }
    }
    __syncthreads();

    for (int c2 = tid; c2 < 2080; c2 += 256) {
        int k = c2 >> 5, sub = c2 & 31, nn = sub >> 4, t = sub & 15;
        int j0 = t * 4;
        int col = (j0 < 32) ? k : 65 + k;
        int cc = col >> 4;
        if (cc >= cbase && cc < cbase + cn) {
            int rlb = nn * 32 + (j0 & 31);
            unsigned long long pk = pack4(Yl[(rlb + 0) * 145 + col], Yl[(rlb + 1) * 145 + col],
                                          Yl[(rlb + 2) * 145 + col], Yl[(rlb + 3) * 145 + col]);
            *(unsigned long long*)(Xb + ((size_t)k * 1024 + n0 + nn) * 64 + j0) = pk;
        }
    }
}

// ---------------------------------------------------------------------------
// Stage B (R9-validated split): 1040 blocks = 65 k x 16 m-tiles (M=64).
__global__ __launch_bounds__(256) void k_einsum(const unsigned short* __restrict__ Xb,
                                                const unsigned short* __restrict__ BmatT,
                                                unsigned short* __restrict__ Y2) {
    __shared__ char lds[8192];
    int tid = threadIdx.x, l = tid & 63, w = tid >> 6;
    int k = blockIdx.x >> 4, mt = blockIdx.x & 15;
    int m0 = mt * 64 + w * 16;
    int lr = l & 15, lq = l >> 4;

    bf16x8 a[2], b[4][2];
    #pragma unroll
    for (int kb = 0; kb < 2; ++kb)
        a[kb] = *(const bf16x8*)(Xb + ((size_t)k * 1024 + m0 + lr) * 64 + kb * 32 + lq * 8);
    #pragma unroll
    for (int cf = 0; cf < 4; ++cf)
        #pragma unroll
        for (int kb = 0; kb < 2; ++kb)
            b[cf][kb] = *(const bf16x8*)(BmatT + ((size_t)k * 64 + cf * 16 + lr) * 64 + kb * 32 + lq * 8);

    f32x4 acc[4];
    #pragma unroll
    for (int cf = 0; cf < 4; ++cf) acc[cf] = (f32x4)0.f;
    #pragma unroll
    for (int cf = 0; cf < 4; ++cf) {
        acc[cf] = __builtin_amdgcn_mfma_f32_16x16x32_bf16(a[0], b[cf][0], acc[cf], 0, 0, 0);
        acc[cf] = __builtin_amdgcn_mfma_f32_16x16x32_bf16(a[1], b[cf][1], acc[cf], 0, 0, 0);
    }

    #pragma unroll
    for (int cf = 0; cf < 4; ++cf)
        #pragma unroll
        for (int rr = 0; rr < 4; ++rr) {
            int row = lq * 4 + rr;             // 0..15 within wave tile
            int col = cf * 16 + lr;
            int byte = w * 2048 + ((row * 128 + col * 2) ^ ((row & 7) << 4));
            *(unsigned short*)(lds + byte) = f2bf(acc[cf][rr]);
        }
    __syncthreads();
    #pragma unroll
    for (int i = 0; i < 2; ++i) {
        int row = i * 8 + (l >> 3);            // 0..15
        int byte = w * 2048 + ((row * 128 + (l & 7) * 16) ^ ((row & 7) << 4));
        bf16x8 v = *(const bf16x8*)(lds + byte);
        *(bf16x8*)(Y2 + ((size_t)k * 1024 + m0 + row) * 64 + (l & 7) * 8) = v;
    }
}

// ---------------------------------------------------------------------------
// Stage C: R3 body, c-split across 2 blocks per n-pair (1024 blocks).
// bid&511 = n-pair; bid>>9 = c-half (0: c 0-3, 1: c 4-7).
__global__ __launch_bounds__(256) void k_idft(const unsigned short* __restrict__ Y2,
                                              const bf16x8* __restrict__ fragCi,
                                              float* __restrict__ out) {
    __shared__ char smem[20480];            // ys[64][160] bf16, swizzled
    int tid = threadIdx.x;
    int np = blockIdx.x & 511, ch = blockIdx.x >> 9;
    int cbase = ch * 4;
    int row0 = np * 64;
    int n0 = np * 2;

    for (int i = tid; i < 1920; i += 256) {
        int rl = i / 30, cp = 130 + i % 30;
        int byte = (rl * 320 + cp * 2) ^ ((rl & 7) << 4);
        *(unsigned short*)(smem + byte) = 0;
    }
    for (int c2 = tid; c2 < 2080; c2 += 256) {
        int k = c2 >> 5, sub = c2 & 31, nn = sub >> 4, t = sub & 15;
        unsigned long long v = *(const unsigned long long*)(Y2 + ((size_t)k * 1024 + n0 + nn) * 64 + t * 4);
        int o2_0 = t * 4;
        int col = (o2_0 < 32) ? k : 65 + k;
        int r0 = nn * 32 + (o2_0 & 31);
        #pragma unroll
        for (int i = 0; i < 4; ++i) {
            int rl = r0 + i;
            int byte = (rl * 320 + col * 2) ^ ((rl & 7) << 4);
            *(unsigned short*)(smem + byte) = (unsigned short)(v >> (16 * i));
        }
    }
    __syncthreads();

    int l = tid & 63, w = tid >> 6;
    int rl_a = w * 16 + (l & 15);
    int coff = (l >> 4) * 16;
    bf16x8 a[5];
    #pragma unroll
    for (int kb = 0; kb < 5; ++kb) {
        int byte = (rl_a * 320 + kb * 64 + coff) ^ ((rl_a & 7) << 4);
        a[kb] = *(const bf16x8*)(smem + byte);
    }
    f32x4 acc[4];
    #pragma unroll
    for (int ci = 0; ci < 4; ++ci) acc[ci] = (f32x4)0.f;
    #pragma unroll
    for (int ci = 0; ci < 4; ++ci)
        #pragma unroll
        for (int kb = 0; kb < 5; ++kb)
            acc[ci] = __builtin_amdgcn_mfma_f32_16x16x32_bf16(a[kb], fragCi[((cbase + ci) * 5 + kb) * 64 + l], acc[ci], 0, 0, 0);

    int rowd = row0 + w * 16 + (l >> 4) * 4;
    int cold = l & 15;
    #pragma unroll
    for (int ci = 0; ci < 4; ++ci)
        #pragma unroll
        for (int r = 0; r < 4; ++r)
            out[(size_t)(rowd + r) * 128 + (cbase + ci) * 16 + cold] = acc[ci][r];
}

// ---------------------------------------------------------------------------
extern "C" void kernel_launch(void* const* d_in, const int* in_sizes, int n_in,
                              void* d_out, int out_size, void* d_ws, size_t ws_size,
                              hipStream_t stream) {
    const float* x = (const float*)d_in[0];
    const float* W = (const float*)d_in[1];
    const float* D = (const float*)d_in[2];
    float* out = (float*)d_out;
    float* ws  = (float*)d_ws;

    unsigned short* BmatT  = (unsigned short*)ws;               // 266240 bf16
    unsigned short* Xb     = (unsigned short*)(ws + 133120);    // 4259840 bf16
    unsigned short* Y2     = (unsigned short*)(ws + 2263040);   // 4259840 bf16
    unsigned short* fragB  = (unsigned short*)(ws + 4392960);   // 18432 bf16
    unsigned short* fragCi = fragB + 18432;                     // 20480 bf16

    k_init_frag<<<80,   256, 0, stream>>>(fragB, fragCi);
    k_wfs_mfma <<<16,   256, 0, stream>>>(W, (const bf16x8*)fragB, BmatT);
    k_fdft     <<<1024, 256, 0, stream>>>(x, D, (const bf16x8*)fragB, Xb);
    k_einsum   <<<1040, 256, 0, stream>>>(Xb, BmatT, Y2);
    k_idft     <<<1024, 256, 0, stream>>>(Y2, (const bf16x8*)fragCi, out);
}